// Round 1
// baseline (410.093 us; speedup 1.0000x reference)
//
#include <hip/hip_runtime.h>
#include <hip/hip_bf16.h>

#define O_N 128
#define D_N 128
#define F_LS 64
#define T_MAX 128
#define FE_N 16
#define H_GRU 64
#define NH 128
#define NO 64
#define PH 128

typedef _Float16 f16;
typedef f16 f16x8 __attribute__((ext_vector_type(8)));
typedef f16 f16x4 __attribute__((ext_vector_type(4)));
typedef float f32x4 __attribute__((ext_vector_type(4)));

__device__ __forceinline__ float fast_sigmoid(float x) {
    return __builtin_amdgcn_rcpf(1.f + __expf(-x));
}
__device__ __forceinline__ float fast_tanh(float x) {
    return 1.f - 2.f * __builtin_amdgcn_rcpf(1.f + __expf(2.f * x));
}

// ---------------- encoders + PA/PB precompute ----------------
// grid 256: block b -> (enc = b>>7, row = b&127); 128 threads
__global__ __launch_bounds__(128) void k_enc(
    const float* __restrict__ O_feats, const float* __restrict__ D_feats,
    const float* __restrict__ WO1, const float* __restrict__ bO1,
    const float* __restrict__ WO2, const float* __restrict__ bO2,
    const float* __restrict__ WO3, const float* __restrict__ bO3,
    const float* __restrict__ WD1, const float* __restrict__ bD1,
    const float* __restrict__ WD2, const float* __restrict__ bD2,
    const float* __restrict__ WD3, const float* __restrict__ bD3,
    const float* __restrict__ Wp1,
    float* __restrict__ PA, float* __restrict__ PB, float* __restrict__ d_out)
{
    __shared__ float h1[NH];
    __shared__ float h2[NH];
    __shared__ float ev[NO];
    const int b = blockIdx.x;
    const int enc = b >> 7;
    const int row = b & 127;
    const int t = threadIdx.x;
    if (b == 0 && t == 0) d_out[0] = 0.f;

    const float* x  = (enc ? D_feats : O_feats) + row * F_LS;
    const float* W1 = enc ? WD1 : WO1;  const float* b1 = enc ? bD1 : bO1;
    const float* W2 = enc ? WD2 : WO2;  const float* b2 = enc ? bD2 : bO2;
    const float* W3 = enc ? WD3 : WO3;  const float* b3 = enc ? bD3 : bO3;

    float a = b1[t];
    #pragma unroll 8
    for (int k = 0; k < F_LS; ++k) a += x[k] * W1[k * NH + t];
    h1[t] = fmaxf(a, 0.f);
    __syncthreads();

    a = b2[t];
    #pragma unroll 8
    for (int k = 0; k < NH; ++k) a += h1[k] * W2[k * NH + t];
    float h2v = fmaxf(a, 0.f);
    h2[t] = h2v;
    __syncthreads();

    if (t < NO) {
        a = b3[t];
        #pragma unroll 8
        for (int k = 0; k < NH; ++k) a += h2[k] * W3[k * NO + t];
        ev[t] = a;
    }
    __syncthreads();

    const float* Wp = Wp1 + (enc ? NO * PH : 0);
    a = 0.f;
    #pragma unroll 8
    for (int k = 0; k < NO; ++k) a += ev[k] * Wp[k * PH + t];
    (enc ? PB : PA)[row * PH + t] = a;
}

// ---------------- pair scores: s_pair = softplus(MLP) ----------------
// grid 128 (i), 128 threads (j)
__global__ __launch_bounds__(128) void k_pair(
    const float* __restrict__ PA, const float* __restrict__ PB,
    const float* __restrict__ bp1, const float* __restrict__ Wp2,
    const float* __restrict__ bp2, float* __restrict__ s_pair)
{
    const int i = blockIdx.x;
    const int j = threadIdx.x;
    __shared__ float pa[PH];
    __shared__ float b1s[PH];
    __shared__ float w2s[PH];
    pa[j]  = PA[i * PH + j];
    b1s[j] = bp1[j];
    w2s[j] = Wp2[j];
    __syncthreads();
    const float* pb = PB + j * PH;
    float acc = 0.f;
    #pragma unroll 8
    for (int c = 0; c < PH; ++c)
        acc += w2s[c] * fmaxf(pa[c] + pb[c] + b1s[c], 0.f);
    float z = acc + bp2[0];
    float sp = fmaxf(z, 0.f) + log1pf(__expf(-fabsf(z)));
    s_pair[i * 128 + j] = sp;
}

// ---------------- GRU: one wave = 16 pairs, MFMA f16 ----------------
// grid 1024 x 64 threads
__global__ __launch_bounds__(64, 1) void k_gru(
    const float* __restrict__ seqs, const int* __restrict__ lengths,
    const float* __restrict__ W_ih, const float* __restrict__ b_ih,
    const float* __restrict__ W_hh, const float* __restrict__ b_hh,
    const float* __restrict__ Ws, const float* __restrict__ bs,
    const float* __restrict__ s_pair, float* __restrict__ d_out)
{
    __shared__ __align__(16) f16 hbuf[16 * 72];   // [pair][64 + 8 pad]
    __shared__ __align__(16) f16 xbuf[16 * 40];   // [pair][16 real | 16 zero | 8 pad]
    const int l  = threadIdx.x;       // 0..63
    const int q  = l >> 4;            // quad
    const int n  = l & 15;
    const int pb = blockIdx.x * 16;

    // --- W fragments, B-operand layout: lane holds W[k = 32*ks + 8*q + j][16*nt + n]
    f16x8 whh[12][2];
    #pragma unroll
    for (int nt = 0; nt < 12; ++nt)
        #pragma unroll
        for (int ks = 0; ks < 2; ++ks)
            #pragma unroll
            for (int j = 0; j < 8; ++j)
                whh[nt][ks][j] = (f16)W_hh[(ks * 32 + q * 8 + j) * 192 + nt * 16 + n];
    f16x8 wih[12];
    #pragma unroll
    for (int nt = 0; nt < 12; ++nt)
        #pragma unroll
        for (int j = 0; j < 8; ++j) {
            int k = q * 8 + j;
            wih[nt][j] = (k < FE_N) ? (f16)W_ih[k * 192 + nt * 16 + n] : (f16)0.f;
        }

    float brz_r[4], brz_z[4], bxn[4], bhn[4], ws_c[4];
    #pragma unroll
    for (int ct = 0; ct < 4; ++ct) {
        int c = n + 16 * ct;
        brz_r[ct] = b_ih[c] + b_hh[c];
        brz_z[ct] = b_ih[64 + c] + b_hh[64 + c];
        bxn[ct]   = b_ih[128 + c];
        bhn[ct]   = b_hh[128 + c];
        ws_c[ct]  = Ws[c];
    }
    int len[4];
    #pragma unroll
    for (int r = 0; r < 4; ++r) len[r] = lengths[pb + q * 4 + r];
    int ml = max(max(len[0], len[1]), max(len[2], len[3]));
    ml = max(ml, __shfl_xor(ml, 16));
    ml = max(ml, __shfl_xor(ml, 32));
    const int maxlen = __builtin_amdgcn_readfirstlane(ml);

    // zero h rows (cols 0..63) and x zero-region (cols 16..31)
    {
        f16x8 z8 = {(f16)0, (f16)0, (f16)0, (f16)0, (f16)0, (f16)0, (f16)0, (f16)0};
        #pragma unroll
        for (int it = 0; it < 2; ++it) {
            int id = l + 64 * it;
            int rr = id >> 3, ch = id & 7;
            *(f16x8*)&hbuf[rr * 72 + ch * 8] = z8;
        }
        if (l < 32) {
            int rr = l >> 1, ch = l & 1;
            *(f16x8*)&xbuf[rr * 40 + 16 + ch * 8] = z8;
        }
    }
    f32x4 hf[4];
    #pragma unroll
    for (int ct = 0; ct < 4; ++ct) hf[ct] = (f32x4){0.f, 0.f, 0.f, 0.f};

    __syncthreads();

    const float4* xp = (const float4*)seqs + (size_t)(pb + (l >> 2)) * (T_MAX * 4) + (l & 3);
    float4 xv = xp[0];
    const f32x4 zero4 = {0.f, 0.f, 0.f, 0.f};

    for (int t = 0; t < maxlen; ++t) {
        // stage x_t (wave-private rows)
        f16x4 xf;
        xf[0] = (f16)xv.x; xf[1] = (f16)xv.y; xf[2] = (f16)xv.z; xf[3] = (f16)xv.w;
        *(f16x4*)&xbuf[(l >> 2) * 40 + (l & 3) * 4] = xf;
        __syncthreads();
        // prefetch next step's x behind the math
        int tn = (t + 1 < maxlen) ? (t + 1) : t;
        xv = xp[tn * 4];

        // A-fragments (m = n, k = 32*ks + 8*q + j)
        f16x8 ah0 = *(const f16x8*)&hbuf[n * 72 + q * 8];
        f16x8 ah1 = *(const f16x8*)&hbuf[n * 72 + 32 + q * 8];
        f16x8 ax  = *(const f16x8*)&xbuf[n * 40 + q * 8];

        f32x4 arz[8], ahn[4], axn[4];
        #pragma unroll
        for (int nt = 0; nt < 8; ++nt) {       // r,z: gx + gh fused pre-activation
            f32x4 a = __builtin_amdgcn_mfma_f32_16x16x32_f16(ah0, whh[nt][0], zero4, 0, 0, 0);
            a = __builtin_amdgcn_mfma_f32_16x16x32_f16(ah1, whh[nt][1], a, 0, 0, 0);
            arz[nt] = __builtin_amdgcn_mfma_f32_16x16x32_f16(ax, wih[nt], a, 0, 0, 0);
        }
        #pragma unroll
        for (int ct = 0; ct < 4; ++ct) {       // n-gate: hn and xn kept separate
            f32x4 a = __builtin_amdgcn_mfma_f32_16x16x32_f16(ah0, whh[8 + ct][0], zero4, 0, 0, 0);
            ahn[ct] = __builtin_amdgcn_mfma_f32_16x16x32_f16(ah1, whh[8 + ct][1], a, 0, 0, 0);
            axn[ct] = __builtin_amdgcn_mfma_f32_16x16x32_f16(ax, wih[8 + ct], zero4, 0, 0, 0);
        }

        // gates; C/D layout: row(pair) = 4*q + r, col(c) = n + 16*ct
        #pragma unroll
        for (int ct = 0; ct < 4; ++ct) {
            #pragma unroll
            for (int r = 0; r < 4; ++r) {
                float rg   = fast_sigmoid(arz[ct][r] + brz_r[ct]);
                float zg   = fast_sigmoid(arz[4 + ct][r] + brz_z[ct]);
                float hn_v = ahn[ct][r] + bhn[ct];
                float xn_v = axn[ct][r] + bxn[ct];
                float nn   = fast_tanh(fmaf(rg, hn_v, xn_v));
                float hold = hf[ct][r];
                float hnew = fmaf(zg, hold - nn, nn);
                hnew = (t < len[r]) ? hnew : hold;
                hf[ct][r] = hnew;
                hbuf[(q * 4 + r) * 72 + n + 16 * ct] = (f16)hnew;
            }
        }
    }

    // epilogue: p_seq = sigmoid(h @ Ws + bs), contrib = s_pair * p_seq
    float part[4];
    #pragma unroll
    for (int r = 0; r < 4; ++r)
        part[r] = hf[0][r] * ws_c[0] + hf[1][r] * ws_c[1] +
                  hf[2][r] * ws_c[2] + hf[3][r] * ws_c[3];
    #pragma unroll
    for (int off = 1; off < 16; off <<= 1)
        #pragma unroll
        for (int r = 0; r < 4; ++r)
            part[r] += __shfl_xor(part[r], off);

    float contrib = 0.f;
    if (n == 0) {
        float bsv = bs[0];
        #pragma unroll
        for (int r = 0; r < 4; ++r) {
            float pv = fast_sigmoid(part[r] + bsv);
            contrib += s_pair[pb + q * 4 + r] * pv;
        }
    }
    contrib += __shfl_xor(contrib, 16);
    contrib += __shfl_xor(contrib, 32);
    if (l == 0) atomicAdd(d_out, contrib);
}

extern "C" void kernel_launch(void* const* d_in, const int* in_sizes, int n_in,
                              void* d_out, int out_size, void* d_ws, size_t ws_size,
                              hipStream_t stream)
{
    const float* O_feats = (const float*)d_in[0];
    const float* D_feats = (const float*)d_in[1];
    const float* seqs    = (const float*)d_in[2];
    const int*   lengths = (const int*)d_in[3];
    const float* WO1 = (const float*)d_in[4];  const float* bO1 = (const float*)d_in[5];
    const float* WO2 = (const float*)d_in[6];  const float* bO2 = (const float*)d_in[7];
    const float* WO3 = (const float*)d_in[8];  const float* bO3 = (const float*)d_in[9];
    const float* WD1 = (const float*)d_in[10]; const float* bD1 = (const float*)d_in[11];
    const float* WD2 = (const float*)d_in[12]; const float* bD2 = (const float*)d_in[13];
    const float* WD3 = (const float*)d_in[14]; const float* bD3 = (const float*)d_in[15];
    const float* Wp1 = (const float*)d_in[16]; const float* bp1 = (const float*)d_in[17];
    const float* Wp2 = (const float*)d_in[18]; const float* bp2 = (const float*)d_in[19];
    const float* W_ih = (const float*)d_in[20]; const float* b_ih = (const float*)d_in[21];
    const float* W_hh = (const float*)d_in[22]; const float* b_hh = (const float*)d_in[23];
    const float* Ws   = (const float*)d_in[24]; const float* bs   = (const float*)d_in[25];

    float* out    = (float*)d_out;
    float* PA     = (float*)d_ws;          // 128*128
    float* PB     = PA + 128 * 128;        // 128*128
    float* s_pair = PB + 128 * 128;        // 16384

    k_enc<<<256, 128, 0, stream>>>(O_feats, D_feats,
                                   WO1, bO1, WO2, bO2, WO3, bO3,
                                   WD1, bD1, WD2, bD2, WD3, bD3,
                                   Wp1, PA, PB, out);
    k_pair<<<128, 128, 0, stream>>>(PA, PB, bp1, Wp2, bp2, s_pair);
    k_gru<<<1024, 64, 0, stream>>>(seqs, lengths, W_ih, b_ih, W_hh, b_hh,
                                   Ws, bs, s_pair, out);
}

// Round 2
// 381.142 us; speedup vs baseline: 1.0760x; 1.0760x over previous
//
#include <hip/hip_runtime.h>
#include <hip/hip_bf16.h>

#define O_N 128
#define D_N 128
#define F_LS 64
#define T_MAX 128
#define FE_N 16
#define H_GRU 64
#define NH 128
#define NO 64
#define PH 128

typedef _Float16 f16;
typedef f16 f16x8 __attribute__((ext_vector_type(8)));
typedef f16 f16x4 __attribute__((ext_vector_type(4)));
typedef float f32x4 __attribute__((ext_vector_type(4)));

__device__ __forceinline__ float fast_sigmoid(float x) {
    return __builtin_amdgcn_rcpf(1.f + __expf(-x));
}
__device__ __forceinline__ float fast_tanh(float x) {
    return 1.f - 2.f * __builtin_amdgcn_rcpf(1.f + __expf(2.f * x));
}

// ---------------- encoders + PA/PB precompute (also zeroes d_out + hist) ----
__global__ __launch_bounds__(128) void k_enc(
    const float* __restrict__ O_feats, const float* __restrict__ D_feats,
    const float* __restrict__ WO1, const float* __restrict__ bO1,
    const float* __restrict__ WO2, const float* __restrict__ bO2,
    const float* __restrict__ WO3, const float* __restrict__ bO3,
    const float* __restrict__ WD1, const float* __restrict__ bD1,
    const float* __restrict__ WD2, const float* __restrict__ bD2,
    const float* __restrict__ WD3, const float* __restrict__ bD3,
    const float* __restrict__ Wp1,
    float* __restrict__ PA, float* __restrict__ PB,
    int* __restrict__ hist, float* __restrict__ d_out)
{
    __shared__ float h1[NH];
    __shared__ float h2[NH];
    __shared__ float ev[NO];
    const int b = blockIdx.x;
    const int enc = b >> 7;
    const int row = b & 127;
    const int t = threadIdx.x;
    if (b == 0) {
        if (t == 0) d_out[0] = 0.f;
        for (int i = t; i <= 128; i += 128) hist[i] = 0;
    }

    const float* x  = (enc ? D_feats : O_feats) + row * F_LS;
    const float* W1 = enc ? WD1 : WO1;  const float* b1 = enc ? bD1 : bO1;
    const float* W2 = enc ? WD2 : WO2;  const float* b2 = enc ? bD2 : bO2;
    const float* W3 = enc ? WD3 : WO3;  const float* b3 = enc ? bD3 : bO3;

    float a = b1[t];
    #pragma unroll 8
    for (int k = 0; k < F_LS; ++k) a += x[k] * W1[k * NH + t];
    h1[t] = fmaxf(a, 0.f);
    __syncthreads();

    a = b2[t];
    #pragma unroll 8
    for (int k = 0; k < NH; ++k) a += h1[k] * W2[k * NH + t];
    h2[t] = fmaxf(a, 0.f);
    __syncthreads();

    if (t < NO) {
        a = b3[t];
        #pragma unroll 8
        for (int k = 0; k < NH; ++k) a += h2[k] * W3[k * NO + t];
        ev[t] = a;
    }
    __syncthreads();

    const float* Wp = Wp1 + (enc ? NO * PH : 0);
    a = 0.f;
    #pragma unroll 8
    for (int k = 0; k < NO; ++k) a += ev[k] * Wp[k * PH + t];
    (enc ? PB : PA)[row * PH + t] = a;
}

// ---------------- pair scores + length histogram ----------------
__global__ __launch_bounds__(128) void k_pair(
    const float* __restrict__ PA, const float* __restrict__ PB,
    const float* __restrict__ bp1, const float* __restrict__ Wp2,
    const float* __restrict__ bp2, const int* __restrict__ lengths,
    float* __restrict__ s_pair, int* __restrict__ hist)
{
    const int i = blockIdx.x;
    const int j = threadIdx.x;
    __shared__ float pa[PH];
    __shared__ float b1s[PH];
    __shared__ float w2s[PH];
    pa[j]  = PA[i * PH + j];
    b1s[j] = bp1[j];
    w2s[j] = Wp2[j];
    __syncthreads();
    const float* pb = PB + j * PH;
    float acc = 0.f;
    #pragma unroll 8
    for (int c = 0; c < PH; ++c)
        acc += w2s[c] * fmaxf(pa[c] + pb[c] + b1s[c], 0.f);
    float z = acc + bp2[0];
    float sp = fmaxf(z, 0.f) + log1pf(__expf(-fabsf(z)));
    s_pair[i * 128 + j] = sp;
    atomicAdd(&hist[lengths[i * 128 + j]], 1);
}

// ---------------- exclusive scan of hist (in place) ----------------
__global__ __launch_bounds__(256) void k_scan(int* __restrict__ hist)
{
    __shared__ int sh[129];
    const int t = threadIdx.x;
    if (t < 129) sh[t] = hist[t];
    __syncthreads();
    if (t == 0) {
        int run = 0;
        for (int i = 0; i <= 128; ++i) { int v = sh[i]; sh[i] = run; run += v; }
    }
    __syncthreads();
    if (t < 129) hist[t] = sh[t];
}

// ---------------- scatter: perm = pair ids sorted by length ----------------
__global__ __launch_bounds__(256) void k_scatter(
    const int* __restrict__ lengths, int* __restrict__ hist, int* __restrict__ perm)
{
    const int i = blockIdx.x * 256 + threadIdx.x;
    const int len = lengths[i];
    const int pos = atomicAdd(&hist[len], 1);
    perm[pos] = i;
}

// ---------------- GRU: 4 waves per 16 pairs, c-split, MFMA f16 ------------
// grid 1024 x 256 threads; wave w owns hidden cols [16w,16w+16)
__global__ __launch_bounds__(256, 4) void k_gru(
    const float* __restrict__ seqs, const int* __restrict__ lengths,
    const int* __restrict__ perm,
    const float* __restrict__ W_ih, const float* __restrict__ b_ih,
    const float* __restrict__ W_hh, const float* __restrict__ b_hh,
    const float* __restrict__ Ws, const float* __restrict__ bs,
    const float* __restrict__ s_pair, float* __restrict__ d_out)
{
    __shared__ __align__(16) f16 hbuf[2 * 16 * 72];   // [buf][pair][64 + 8 pad]
    __shared__ __align__(16) f16 xbuf[2 * 16 * 40];   // [buf][pair][16 | 16 zero | 8 pad]
    __shared__ float red[64];
    const int tid = threadIdx.x;
    const int w  = tid >> 6;          // wave 0..3
    const int l  = tid & 63;
    const int q  = l >> 4;
    const int n  = l & 15;
    const int c  = w * 16 + n;        // this lane's hidden column
    const int pb = blockIdx.x * 16;

    // B-fragments: lane holds W[k = ks*32 + q*8 + j][gate_base + c]
    f16x8 wh[3][2], wi[3];
    #pragma unroll
    for (int g = 0; g < 3; ++g) {
        const int gb = g * 64;
        #pragma unroll
        for (int ks = 0; ks < 2; ++ks)
            #pragma unroll
            for (int j = 0; j < 8; ++j)
                wh[g][ks][j] = (f16)W_hh[(ks * 32 + q * 8 + j) * 192 + gb + c];
        #pragma unroll
        for (int j = 0; j < 8; ++j) {
            int k = q * 8 + j;
            wi[g][j] = (k < FE_N) ? (f16)W_ih[k * 192 + gb + c] : (f16)0.f;
        }
    }

    const float brz_r = b_ih[c] + b_hh[c];
    const float brz_z = b_ih[64 + c] + b_hh[64 + c];
    const float bxn   = b_ih[128 + c];
    const float bhn   = b_hh[128 + c];
    const float wsc   = Ws[c];

    int pr[4], len[4];
    #pragma unroll
    for (int r = 0; r < 4; ++r) {
        pr[r]  = perm[pb + q * 4 + r];
        len[r] = lengths[pr[r]];
    }
    int ml = max(max(len[0], len[1]), max(len[2], len[3]));
    ml = max(ml, __shfl_xor(ml, 16));
    ml = max(ml, __shfl_xor(ml, 32));
    const int maxlen = __builtin_amdgcn_readfirstlane(ml);

    // zero hbuf[0] and both xbuf zero-regions
    {
        f16x8 z8 = {(f16)0, (f16)0, (f16)0, (f16)0, (f16)0, (f16)0, (f16)0, (f16)0};
        if (tid < 144) *(f16x8*)&hbuf[tid * 8] = z8;
        if (tid >= 192) {  // 64 threads: 32 chunks per buffer
            int id = tid - 192;          // 0..63
            int buf = id >> 5;           // 0,1
            int rr = (id & 31) >> 1, ch = id & 1;
            *(f16x8*)&xbuf[buf * 640 + rr * 40 + 16 + ch * 8] = z8;
        }
    }

    // x staging: thread -> (pair tid>>4, feat tid&15)
    const int pl = tid >> 4, ft = tid & 15;
    const int pp = perm[pb + pl];
    const float* xptr = seqs + (size_t)pp * (T_MAX * FE_N) + ft;
    xbuf[pl * 40 + ft] = (f16)xptr[0];                       // x_0 -> buf 0
    float xv = xptr[((1 < maxlen) ? 1 : (maxlen - 1)) * 16]; // x_1 in reg

    float hold[4] = {0.f, 0.f, 0.f, 0.f};
    const f32x4 zero4 = {0.f, 0.f, 0.f, 0.f};
    __syncthreads();

    for (int t = 0; t < maxlen; ++t) {
        const f16* hb  = hbuf + (t & 1) * 1152;
        f16*       hbn = hbuf + ((t + 1) & 1) * 1152;
        const f16* xb  = xbuf + (t & 1) * 640;
        f16*       xbn = xbuf + ((t + 1) & 1) * 640;

        f16x8 ah0 = *(const f16x8*)&hb[n * 72 + q * 8];
        f16x8 ah1 = *(const f16x8*)&hb[n * 72 + 32 + q * 8];
        f16x8 ax  = *(const f16x8*)&xb[n * 40 + q * 8];

        // stage x_{t+1} into next buffer; prefetch x_{t+2}
        xbn[pl * 40 + ft] = (f16)xv;
        int tn = (t + 2 < maxlen) ? (t + 2) : (maxlen - 1);
        xv = xptr[tn * 16];

        f32x4 ar = __builtin_amdgcn_mfma_f32_16x16x32_f16(ah0, wh[0][0], zero4, 0, 0, 0);
        ar = __builtin_amdgcn_mfma_f32_16x16x32_f16(ah1, wh[0][1], ar, 0, 0, 0);
        ar = __builtin_amdgcn_mfma_f32_16x16x32_f16(ax,  wi[0],    ar, 0, 0, 0);
        f32x4 az = __builtin_amdgcn_mfma_f32_16x16x32_f16(ah0, wh[1][0], zero4, 0, 0, 0);
        az = __builtin_amdgcn_mfma_f32_16x16x32_f16(ah1, wh[1][1], az, 0, 0, 0);
        az = __builtin_amdgcn_mfma_f32_16x16x32_f16(ax,  wi[1],    az, 0, 0, 0);
        f32x4 ahn = __builtin_amdgcn_mfma_f32_16x16x32_f16(ah0, wh[2][0], zero4, 0, 0, 0);
        ahn = __builtin_amdgcn_mfma_f32_16x16x32_f16(ah1, wh[2][1], ahn, 0, 0, 0);
        f32x4 axn = __builtin_amdgcn_mfma_f32_16x16x32_f16(ax, wi[2], zero4, 0, 0, 0);

        // C/D layout: row(pair) = 4q + r, col = c (fixed per lane)
        #pragma unroll
        for (int r = 0; r < 4; ++r) {
            float rg   = fast_sigmoid(ar[r] + brz_r);
            float zg   = fast_sigmoid(az[r] + brz_z);
            float nn   = fast_tanh(fmaf(rg, ahn[r] + bhn, axn[r] + bxn));
            float hnew = fmaf(zg, hold[r] - nn, nn);
            hnew = (t < len[r]) ? hnew : hold[r];
            hold[r] = hnew;
            hbn[(q * 4 + r) * 72 + c] = (f16)hnew;
        }
        __syncthreads();
    }

    // epilogue: p_seq = sigmoid(h @ Ws + bs); contrib = s_pair * p_seq
    float part[4];
    #pragma unroll
    for (int r = 0; r < 4; ++r) part[r] = hold[r] * wsc;
    #pragma unroll
    for (int off = 1; off < 16; off <<= 1)
        #pragma unroll
        for (int r = 0; r < 4; ++r)
            part[r] += __shfl_xor(part[r], off);
    if (n == 0) {
        #pragma unroll
        for (int r = 0; r < 4; ++r) red[w * 16 + q * 4 + r] = part[r];
    }
    __syncthreads();
    if (tid < 16) {
        float s = red[tid] + red[16 + tid] + red[32 + tid] + red[48 + tid];
        float pv = fast_sigmoid(s + bs[0]);
        float contrib = s_pair[perm[pb + tid]] * pv;
        #pragma unroll
        for (int off = 1; off < 16; off <<= 1)
            contrib += __shfl_xor(contrib, off);
        if (tid == 0) atomicAdd(d_out, contrib);
    }
}

extern "C" void kernel_launch(void* const* d_in, const int* in_sizes, int n_in,
                              void* d_out, int out_size, void* d_ws, size_t ws_size,
                              hipStream_t stream)
{
    const float* O_feats = (const float*)d_in[0];
    const float* D_feats = (const float*)d_in[1];
    const float* seqs    = (const float*)d_in[2];
    const int*   lengths = (const int*)d_in[3];
    const float* WO1 = (const float*)d_in[4];  const float* bO1 = (const float*)d_in[5];
    const float* WO2 = (const float*)d_in[6];  const float* bO2 = (const float*)d_in[7];
    const float* WO3 = (const float*)d_in[8];  const float* bO3 = (const float*)d_in[9];
    const float* WD1 = (const float*)d_in[10]; const float* bD1 = (const float*)d_in[11];
    const float* WD2 = (const float*)d_in[12]; const float* bD2 = (const float*)d_in[13];
    const float* WD3 = (const float*)d_in[14]; const float* bD3 = (const float*)d_in[15];
    const float* Wp1 = (const float*)d_in[16]; const float* bp1 = (const float*)d_in[17];
    const float* Wp2 = (const float*)d_in[18]; const float* bp2 = (const float*)d_in[19];
    const float* W_ih = (const float*)d_in[20]; const float* b_ih = (const float*)d_in[21];
    const float* W_hh = (const float*)d_in[22]; const float* b_hh = (const float*)d_in[23];
    const float* Ws   = (const float*)d_in[24]; const float* bs   = (const float*)d_in[25];

    float* out    = (float*)d_out;
    float* PA     = (float*)d_ws;              // 16384 f
    float* PB     = PA + 128 * 128;            // 16384 f
    float* s_pair = PB + 128 * 128;            // 16384 f
    int*   hist   = (int*)(s_pair + 16384);    // 256 i (129 used)
    int*   perm   = hist + 256;                // 16384 i

    k_enc<<<256, 128, 0, stream>>>(O_feats, D_feats,
                                   WO1, bO1, WO2, bO2, WO3, bO3,
                                   WD1, bD1, WD2, bD2, WD3, bD3,
                                   Wp1, PA, PB, hist, out);
    k_pair<<<128, 128, 0, stream>>>(PA, PB, bp1, Wp2, bp2, lengths, s_pair, hist);
    k_scan<<<1, 256, 0, stream>>>(hist);
    k_scatter<<<64, 256, 0, stream>>>(lengths, hist, perm);
    k_gru<<<1024, 256, 0, stream>>>(seqs, lengths, perm, W_ih, b_ih, W_hh, b_hh,
                                    Ws, bs, s_pair, out);
}